// Round 10
// baseline (722.822 us; speedup 1.0000x reference)
//
#include <hip/hip_runtime.h>

#define CAR 8
#define SROW 520   // CAR + 64*CAR
#define HID 256
#define EOUT 257
#define XPAD 288   // padded Q-input row (shorts): 8 self + 257 enc + pad
#define ADIM 30

typedef __attribute__((ext_vector_type(8))) short sh8;
typedef __attribute__((ext_vector_type(4))) float f32x4;

__device__ __forceinline__ short f2bf(float f) {
  unsigned u = __builtin_bit_cast(unsigned, f);
  u += 0x7fffu + ((u >> 16) & 1u);   // RNE
  return (short)(u >> 16);
}
// pack two fp32 -> packed bf16x2 (RNE, 5 VALU)
__device__ __forceinline__ unsigned f2bf2(float a, float b) {
  unsigned ua = __builtin_bit_cast(unsigned, a);
  ua += 0x7fffu + ((ua >> 16) & 1u);
  unsigned ub = __builtin_bit_cast(unsigned, b);
  ub += 0x7fffu + ((ub >> 16) & 1u);
  return __builtin_amdgcn_perm(ub, ua, 0x07060302);  // [a.hi16 | b.hi16]
}
// pack two fp32 -> packed bf16x2 (TRUNC, 1 VALU) — h staging only
__device__ __forceinline__ unsigned pkt(float a, float b) {
  return __builtin_amdgcn_perm(__builtin_bit_cast(unsigned, b),
                               __builtin_bit_cast(unsigned, a), 0x07060302);
}

// ---------------------------------------------------------------------------
// Prep: swizzle weights to bf16 MFMA fragments (16x16x32 convention:
// A[m=lane&15][k=quad*8+j], B[k=quad*8+j][n=lane&15], C/D row=quad*4+reg,
// col=lane&15).
// w1f : [W1;b1]^T as A [16 mt][64][8]  (k=8 row = b1)            (8192)
// w2f : W2 as B [17 nt][8 ks][64][8]  nt-major -> base+imm       (69632)
// w3f : Qw1 as B   [9 ks][16 nt][64][8], k = X-row idx           (73728)
// wq2f: Qw2 as B   [8 ks][2 nt][64][8]                           (8192)
// ---------------------------------------------------------------------------
__global__ void k_prep(const float* __restrict__ W1, const float* __restrict__ b1,
                       const float* __restrict__ W2,
                       const float* __restrict__ Qw1, const float* __restrict__ Qw2,
                       short* __restrict__ w1f, short* __restrict__ w2f,
                       short* __restrict__ w3f, short* __restrict__ wq2f) {
  int idx = blockIdx.x * 256 + threadIdx.x;
  if (idx < 8192) {                         // [W1;b1]^T as A
    int mt = idx >> 9, r = idx & 511, lane = r >> 3, j = r & 7;
    int quad = lane >> 4, m = lane & 15;
    int hid = mt * 16 + m;
    float v = (quad == 0) ? W1[j * HID + hid]
            : (quad == 1 && j == 0) ? b1[hid] : 0.0f;
    w1f[idx] = f2bf(v);
    return;
  }
  int i2 = idx - 8192;
  if (i2 < 69632) {                         // W2 as B, [nt][8 ks][64][8]
    int nt = i2 >> 12, r = i2 & 4095;
    int ks = r >> 9, r2 = r & 511, lane = r2 >> 3, j = r2 & 7;
    int quad = lane >> 4, m = lane & 15;
    int k = ks * 32 + quad * 8 + j, n = nt * 16 + m;
    float v = (n < EOUT) ? W2[k * EOUT + n] : 0.0f;
    w2f[i2] = f2bf(v);
    return;
  }
  int i3 = i2 - 69632;
  if (i3 < 73728) {                         // Qw1 as B
    int ks = i3 >> 13, r = i3 & 8191;
    int nt = r >> 9, r2 = r & 511, lane = r2 >> 3, j = r2 & 7;
    int quad = lane >> 4, m = lane & 15;
    int k = ks * 32 + quad * 8 + j, n = nt * 16 + m;
    float v = (k < 265) ? Qw1[k * HID + n] : 0.0f;
    w3f[i3] = f2bf(v);
    return;
  }
  int i4 = i3 - 73728;
  if (i4 < 8192) {                          // Qw2 as B
    int ks = i4 >> 10, r = i4 & 1023;
    int nt = r >> 9, r2 = r & 511, lane = r2 >> 3, j = r2 & 7;
    int quad = lane >> 4, m = lane & 15;
    int k = ks * 32 + quad * 8 + j, n = nt * 16 + m;
    float v = (n < ADIM) ? Qw2[k * ADIM + n] : 0.0f;
    wq2f[i4] = f2bf(v);
  }
}

// ---------------------------------------------------------------------------
// K1: encoder + pool, NB=1, 4 waves, EXACTLY 32 KB LDS -> 5 blocks/CU.
// Phase 1: every wave loads all 64 agent rows (coalesced, L1-hot) -> ballot
//   gives ninv in-registers (no LDS); wave w builds B-frag for its agents
//   16w..16w+15 via shfl (b1 folded as k=8 input, mask at source);
//   16 MFMAs; trunc-pack h -> hlds [Mt][8 ks][64][8].
// Phase 2: wave w owns e-tiles {4w..4w+3}, 8 ks, A/B 1-ahead dbuf,
//   base+imm addressing; tile-16 (col 256) K-split w:{w,w+4} with Bt
//   prefetched BEFORE the loop.
// Phase 3: relu+pool + b2 epilogue -> bf16 sob; psum overlaid into hlds
//   between barriers for the col-256 combine.
// ---------------------------------------------------------------------------
__global__ __launch_bounds__(256, 5)
void k_enc(const float* __restrict__ s, const short* __restrict__ w1f,
           const short* __restrict__ w2f, const float* __restrict__ b2,
           short* __restrict__ sob, int B) {
  __shared__ __align__(16) short hlds[4 * 8 * 512];   // 32768 B exactly
  float* psum = (float*)hlds;        // overlay, valid only after barrier-1

  const int tid = threadIdx.x;
  const int w = tid >> 6, lane = tid & 63;
  const int q = lane >> 4, m = lane & 15;
  const int b = blockIdx.x;
  const float* srow0 = s + (size_t)b * SROW + CAR;

  // ---- phase 1: every wave loads agent `lane` fully ----
  const float* sr = srow0 + lane * CAR;
  float4 f0 = ((const float4*)sr)[0], f1 = ((const float4*)sr)[1];
  int inv = (f0.x == -1.f) | (f0.y == -1.f) | (f0.z == -1.f) | (f0.w == -1.f) |
            (f1.x == -1.f) | (f1.y == -1.f) | (f1.z == -1.f) | (f1.w == -1.f);
  unsigned long long bal = __ballot(inv);
  const float ninv = (float)__popcll(bal);   // same in all waves
  int4 pk = {0, 0, 0, 0};
  if (!inv) {
    pk.x = (int)f2bf2(f0.x, f0.y); pk.y = (int)f2bf2(f0.z, f0.w);
    pk.z = (int)f2bf2(f1.x, f1.y); pk.w = (int)f2bf2(f1.z, f1.w);
  }
  const int src = 16 * w + m;        // agent for this wave's B-frag col m
  int g0 = __shfl(pk.x, src, 64), g1 = __shfl(pk.y, src, 64);
  int g2 = __shfl(pk.z, src, 64), g3 = __shfl(pk.w, src, 64);
  int invm = __shfl(inv, src, 64);
  int4 bv;
  if (q == 0)      bv = (int4){g0, g1, g2, g3};
  else if (q == 1) bv = (int4){invm ? 0 : 0x3f80, 0, 0, 0};  // k=8 bias input
  else             bv = (int4){0, 0, 0, 0};
  sh8 bs = __builtin_bit_cast(sh8, bv);

#pragma unroll
  for (int mt = 0; mt < 16; ++mt) {
    sh8 af = *(const sh8*)(w1f + (mt * 64 + lane) * 8);
    f32x4 z = {0.f, 0.f, 0.f, 0.f};
    f32x4 c = __builtin_amdgcn_mfma_f32_16x16x32_bf16(af, bs, z, 0, 0, 0);
    const int hidb = mt * 16 + q * 4;
    const int ks = hidb >> 5, qB = (hidb >> 3) & 3, js = hidb & 7;
    uint2 k0;
    k0.x = pkt(fmaxf(c[0], 0.f), fmaxf(c[1], 0.f));
    k0.y = pkt(fmaxf(c[2], 0.f), fmaxf(c[3], 0.f));
    *(uint2*)(&hlds[((w * 8 + ks) * 64 + qB * 16 + m) * 8 + js]) = k0;
  }
  __syncthreads();

  // ---- phase 2 ----
  f32x4 acc[4][4];
  f32x4 acc16[4];
#pragma unroll
  for (int Mt = 0; Mt < 4; ++Mt) {
#pragma unroll
    for (int i = 0; i < 4; ++i) {
      f32x4 z = {0.f, 0.f, 0.f, 0.f};
      acc[Mt][i] = z;
    }
    f32x4 z = {0.f, 0.f, 0.f, 0.f};
    acc16[Mt] = z;
  }

  const short* w2b = w2f + (size_t)(4 * w) * 8 * 512 + lane * 8;  // wave base
  const short* hb  = hlds + lane * 8;
  // prefetch tile-16 B-frags for this wave's two K-slices
  sh8 Bt0 = *(const sh8*)(w2f + (size_t)(16 * 8 + w) * 512 + lane * 8);
  sh8 Bt1 = *(const sh8*)(w2f + (size_t)(16 * 8 + w + 4) * 512 + lane * 8);

  sh8 A[4], Bf[4];
#pragma unroll
  for (int Mt = 0; Mt < 4; ++Mt) A[Mt] = *(const sh8*)(hb + (Mt * 8) * 512);
#pragma unroll
  for (int i = 0; i < 4; ++i)    Bf[i] = *(const sh8*)(w2b + (i * 8) * 512);

#pragma unroll
  for (int ks = 0; ks < 8; ++ks) {
    sh8 An[4], Bn[4];
    if (ks < 7) {
#pragma unroll
      for (int Mt = 0; Mt < 4; ++Mt)
        An[Mt] = *(const sh8*)(hb + (Mt * 8 + ks + 1) * 512);
#pragma unroll
      for (int i = 0; i < 4; ++i)
        Bn[i] = *(const sh8*)(w2b + (i * 8 + ks + 1) * 512);
    }
#pragma unroll
    for (int i = 0; i < 4; ++i)
#pragma unroll
      for (int Mt = 0; Mt < 4; ++Mt)
        acc[Mt][i] = __builtin_amdgcn_mfma_f32_16x16x32_bf16(A[Mt], Bf[i], acc[Mt][i], 0, 0, 0);
    if (ks == w) {
#pragma unroll
      for (int Mt = 0; Mt < 4; ++Mt)
        acc16[Mt] = __builtin_amdgcn_mfma_f32_16x16x32_bf16(A[Mt], Bt0, acc16[Mt], 0, 0, 0);
    }
    if (ks == w + 4) {
#pragma unroll
      for (int Mt = 0; Mt < 4; ++Mt)
        acc16[Mt] = __builtin_amdgcn_mfma_f32_16x16x32_bf16(A[Mt], Bt1, acc16[Mt], 0, 0, 0);
    }
    if (ks < 7) {
#pragma unroll
      for (int Mt = 0; Mt < 4; ++Mt) A[Mt] = An[Mt];
#pragma unroll
      for (int i = 0; i < 4; ++i)    Bf[i] = Bn[i];
    }
  }

  // ---- phase 3: relu + b2 + pool (regs/global only, before barrier) ----
#pragma unroll
  for (int i = 0; i < 4; ++i) {
    const int col = (4 * w + i) * 16 + m;          // 0..255
    const float b2c = b2[col];
    float ssum = 0.f;
#pragma unroll
    for (int Mt = 0; Mt < 4; ++Mt)
#pragma unroll
      for (int r = 0; r < 4; ++r)
        ssum += fmaxf(acc[Mt][i][r] + b2c, 0.f);
    ssum += __shfl_xor(ssum, 16, 64);
    ssum += __shfl_xor(ssum, 32, 64);
    ssum -= ninv * fmaxf(b2c, 0.f);
    if (q == 0)
      sob[(size_t)b * XPAD + CAR + col] = f2bf(ssum);
  }
  __syncthreads();                   // barrier-1: all hlds reads done
  if (m == 0) {                      // tile-16: only col 256 matters
#pragma unroll
    for (int Mt = 0; Mt < 4; ++Mt)
#pragma unroll
      for (int r = 0; r < 4; ++r)
        psum[w * 64 + Mt * 16 + q * 4 + r] = acc16[Mt][r];
  }
  __syncthreads();                   // barrier-2

  if (w == 0) {                      // combine K-partials, relu+b2, pool
    float tot = psum[lane] + psum[64 + lane] + psum[128 + lane] + psum[192 + lane];
    const float b2c = b2[256];
    float v = fmaxf(tot + b2c, 0.f);
#pragma unroll
    for (int msk = 1; msk < 64; msk <<= 1)
      v += __shfl_xor(v, msk, 64);
    if (lane == 0)
      sob[(size_t)b * XPAD + CAR + 256] = f2bf(v - ninv * fmaxf(b2c, 0.f));
  }
  if (w == 1 && lane < CAR)          // self-state
    sob[(size_t)b * XPAD + lane] = f2bf(s[(size_t)b * SROW + lane]);
  // pad cols 265..287: poison (finite bf16) x zero w3f rows = 0 in k_q
}

// ---------------------------------------------------------------------------
// K2: Q-head. 4 waves, 16 batch rows/block (512 blocks -> 2/CU).
// GEMM1: wave w owns hid-tiles 4w..4w+3; H fp32 -> LDS (stride 260).
// GEMM2: waves 0-1 (nt = w), K=256; C-layout store.
// ---------------------------------------------------------------------------
__global__ __launch_bounds__(256, 2)
void k_q(const short* __restrict__ sob, const short* __restrict__ w3f,
         const float* __restrict__ Qb1, const short* __restrict__ wq2f,
         const float* __restrict__ Qb2, float* __restrict__ out, int B) {
  __shared__ __align__(16) float H[16 * 260];   // 16.6 KB
  const int tid = threadIdx.x;
  const int w = tid >> 6, lane = tid & 63;
  const int q = lane >> 4, m = lane & 15;
  const int b0 = blockIdx.x * 16;
  int r0 = b0 + m; if (r0 >= B) r0 = B - 1;
  const short* xr0 = sob + (size_t)r0 * XPAD + q * 8;

  f32x4 acc1[4];
#pragma unroll
  for (int i = 0; i < 4; ++i) {
    f32x4 z = {0.f, 0.f, 0.f, 0.f};
    acc1[i] = z;
  }
#pragma unroll
  for (int ks = 0; ks < 9; ++ks) {
    sh8 A0 = *(const sh8*)(xr0 + ks * 32);
#pragma unroll
    for (int i = 0; i < 4; ++i) {
      sh8 Bf = *(const sh8*)(w3f + ((ks * 16 + 4 * w + i) * 64 + lane) * 8);
      acc1[i] = __builtin_amdgcn_mfma_f32_16x16x32_bf16(A0, Bf, acc1[i], 0, 0, 0);
    }
  }
#pragma unroll
  for (int i = 0; i < 4; ++i) {
    const int hcol = (4 * w + i) * 16 + m;
    const float bq = Qb1[hcol];
#pragma unroll
    for (int r = 0; r < 4; ++r)
      H[(q * 4 + r) * 260 + hcol] = fmaxf(acc1[i][r] + bq, 0.f);
  }
  __syncthreads();

  if (w < 2) {                       // GEMM2: H(16x256) @ Qw2 -> out
    const int nt2 = w;
    f32x4 acc2 = {0.f, 0.f, 0.f, 0.f};
#pragma unroll
    for (int ks = 0; ks < 8; ++ks) {
      const float* hp = H + m * 260 + ks * 32 + q * 8;
      float4 ha = ((const float4*)hp)[0], hb = ((const float4*)hp)[1];
      int4 t = {(int)f2bf2(ha.x, ha.y), (int)f2bf2(ha.z, ha.w),
                (int)f2bf2(hb.x, hb.y), (int)f2bf2(hb.z, hb.w)};
      sh8 A2 = __builtin_bit_cast(sh8, t);
      sh8 Bf = *(const sh8*)(wq2f + ((ks * 2 + nt2) * 64 + lane) * 8);
      acc2 = __builtin_amdgcn_mfma_f32_16x16x32_bf16(A2, Bf, acc2, 0, 0, 0);
    }
    const int act = nt2 * 16 + m;
    if (act < ADIM) {
      const float bq = Qb2[act];
#pragma unroll
      for (int r = 0; r < 4; ++r) {
        const int row = b0 + q * 4 + r;
        if (row < B) out[(size_t)row * ADIM + act] = acc2[r] + bq;
      }
    }
  }
}

extern "C" void kernel_launch(void* const* d_in, const int* in_sizes, int n_in,
                              void* d_out, int out_size, void* d_ws, size_t ws_size,
                              hipStream_t stream) {
  const float* s   = (const float*)d_in[0];
  const float* W1  = (const float*)d_in[1];
  const float* b1  = (const float*)d_in[2];
  const float* W2  = (const float*)d_in[3];
  const float* b2  = (const float*)d_in[4];
  const float* Qw1 = (const float*)d_in[5];
  const float* Qb1 = (const float*)d_in[6];
  const float* Qw2 = (const float*)d_in[7];
  const float* Qb2 = (const float*)d_in[8];
  float* out = (float*)d_out;
  const int B = in_sizes[0] / SROW;

  // ws: [sob B*288 bf16][w1f 8192][w2f 69632][w3f 73728][wq2f 8192] shorts
  char* wsb = (char*)d_ws;
  short* sob = (short*)wsb;
  size_t off = (size_t)B * XPAD * sizeof(short);
  short* w1f  = (short*)(wsb + off);            off += 8192 * 2;
  short* w2f  = (short*)(wsb + off);            off += 69632 * 2;
  short* w3f  = (short*)(wsb + off);            off += 73728 * 2;
  short* wq2f = (short*)(wsb + off);

  const int prep_elems = 8192 + 69632 + 73728 + 8192;
  k_prep<<<(prep_elems + 255) / 256, 256, 0, stream>>>(W1, b1, W2, Qw1, Qw2,
                                                       w1f, w2f, w3f, wq2f);
  k_enc<<<B, 256, 0, stream>>>(s, w1f, w2f, b2, sob, B);
  k_q<<<(B + 15) / 16, 256, 0, stream>>>(sob, w3f, Qb1, wq2f, Qb2, out, B);
}

// Round 11
// 183.860 us; speedup vs baseline: 3.9314x; 3.9314x over previous
//
#include <hip/hip_runtime.h>

#define CAR 8
#define SROW 520   // CAR + 64*CAR
#define HID 256
#define EOUT 257
#define XPAD 288   // padded Q-input row (shorts): 8 self + 257 enc + pad
#define ADIM 30

typedef __attribute__((ext_vector_type(8))) short sh8;
typedef __attribute__((ext_vector_type(4))) float f32x4;

__device__ __forceinline__ short f2bf(float f) {
  unsigned u = __builtin_bit_cast(unsigned, f);
  u += 0x7fffu + ((u >> 16) & 1u);   // RNE
  return (short)(u >> 16);
}
// pack two fp32 -> packed bf16x2 (RNE, 5 VALU)
__device__ __forceinline__ unsigned f2bf2(float a, float b) {
  unsigned ua = __builtin_bit_cast(unsigned, a);
  ua += 0x7fffu + ((ua >> 16) & 1u);
  unsigned ub = __builtin_bit_cast(unsigned, b);
  ub += 0x7fffu + ((ub >> 16) & 1u);
  return __builtin_amdgcn_perm(ub, ua, 0x07060302);  // [a.hi16 | b.hi16]
}
// pack two fp32 -> packed bf16x2 (TRUNC, 1 VALU) — h staging only
__device__ __forceinline__ unsigned pkt(float a, float b) {
  return __builtin_amdgcn_perm(__builtin_bit_cast(unsigned, b),
                               __builtin_bit_cast(unsigned, a), 0x07060302);
}

// ---------------------------------------------------------------------------
// Prep: swizzle weights to bf16 MFMA fragments (16x16x32 convention:
// A[m=lane&15][k=quad*8+j], B[k=quad*8+j][n=lane&15], C/D row=quad*4+reg,
// col=lane&15).
// w1f : [W1;b1]^T as A [16 mt][64][8]  (k=8 row = b1)            (8192)
// w2f : W2 as B [17 nt][8 ks][64][8]  nt-major -> base+imm       (69632)
// w3f : Qw1 as B   [9 ks][16 nt][64][8], k = X-row idx           (73728)
// wq2f: Qw2 as B   [8 ks][2 nt][64][8]                           (8192)
// ---------------------------------------------------------------------------
__global__ void k_prep(const float* __restrict__ W1, const float* __restrict__ b1,
                       const float* __restrict__ W2,
                       const float* __restrict__ Qw1, const float* __restrict__ Qw2,
                       short* __restrict__ w1f, short* __restrict__ w2f,
                       short* __restrict__ w3f, short* __restrict__ wq2f) {
  int idx = blockIdx.x * 256 + threadIdx.x;
  if (idx < 8192) {                         // [W1;b1]^T as A
    int mt = idx >> 9, r = idx & 511, lane = r >> 3, j = r & 7;
    int quad = lane >> 4, m = lane & 15;
    int hid = mt * 16 + m;
    float v = (quad == 0) ? W1[j * HID + hid]
            : (quad == 1 && j == 0) ? b1[hid] : 0.0f;
    w1f[idx] = f2bf(v);
    return;
  }
  int i2 = idx - 8192;
  if (i2 < 69632) {                         // W2 as B, [nt][8 ks][64][8]
    int nt = i2 >> 12, r = i2 & 4095;
    int ks = r >> 9, r2 = r & 511, lane = r2 >> 3, j = r2 & 7;
    int quad = lane >> 4, m = lane & 15;
    int k = ks * 32 + quad * 8 + j, n = nt * 16 + m;
    float v = (n < EOUT) ? W2[k * EOUT + n] : 0.0f;
    w2f[i2] = f2bf(v);
    return;
  }
  int i3 = i2 - 69632;
  if (i3 < 73728) {                         // Qw1 as B
    int ks = i3 >> 13, r = i3 & 8191;
    int nt = r >> 9, r2 = r & 511, lane = r2 >> 3, j = r2 & 7;
    int quad = lane >> 4, m = lane & 15;
    int k = ks * 32 + quad * 8 + j, n = nt * 16 + m;
    float v = (k < 265) ? Qw1[k * HID + n] : 0.0f;
    w3f[i3] = f2bf(v);
    return;
  }
  int i4 = i3 - 73728;
  if (i4 < 8192) {                          // Qw2 as B
    int ks = i4 >> 10, r = i4 & 1023;
    int nt = r >> 9, r2 = r & 511, lane = r2 >> 3, j = r2 & 7;
    int quad = lane >> 4, m = lane & 15;
    int k = ks * 32 + quad * 8 + j, n = nt * 16 + m;
    float v = (n < ADIM) ? Qw2[k * ADIM + n] : 0.0f;
    wq2f[i4] = f2bf(v);
  }
}

// ---------------------------------------------------------------------------
// K1: encoder + pool, NB=1, 4 waves, 32 KB LDS.
// __launch_bounds__(256,3): R10's (256,5) clamped VGPRs to ~96 and spilled
// the ~150-reg phase-2 working set to scratch (869 MB FETCH, 7x regression).
// 3 waves/EU caps at ~170 VGPRs — allocator lands at ~84, no spill, and LDS
// (32 KB) still admits up to 5 resident blocks/CU.
// Phase 1: every wave loads all 64 agent rows (coalesced, L1-hot) -> ballot
//   ninv in-registers; wave w builds B-frag for agents 16w..16w+15 via shfl
//   (b1 folded as k=8 input, mask at source); 16 MFMAs; trunc-pack h ->
//   hlds [Mt][8 ks][64][8].
// Phase 2: wave w owns e-tiles {4w..4w+3}, 8 ks, A/B 1-ahead dbuf,
//   base+imm addressing; tile-16 (col 256) K-split w:{w,w+4}, Bt prefetched.
// Phase 3: relu+b2+pool -> bf16 sob; psum overlaid into hlds between
//   barriers for the col-256 combine.
// ---------------------------------------------------------------------------
__global__ __launch_bounds__(256, 3)
void k_enc(const float* __restrict__ s, const short* __restrict__ w1f,
           const short* __restrict__ w2f, const float* __restrict__ b2,
           short* __restrict__ sob, int B) {
  __shared__ __align__(16) short hlds[4 * 8 * 512];   // 32768 B exactly
  float* psum = (float*)hlds;        // overlay, valid only after barrier-1

  const int tid = threadIdx.x;
  const int w = tid >> 6, lane = tid & 63;
  const int q = lane >> 4, m = lane & 15;
  const int b = blockIdx.x;
  const float* srow0 = s + (size_t)b * SROW + CAR;

  // ---- phase 1: every wave loads agent `lane` fully ----
  const float* sr = srow0 + lane * CAR;
  float4 f0 = ((const float4*)sr)[0], f1 = ((const float4*)sr)[1];
  int inv = (f0.x == -1.f) | (f0.y == -1.f) | (f0.z == -1.f) | (f0.w == -1.f) |
            (f1.x == -1.f) | (f1.y == -1.f) | (f1.z == -1.f) | (f1.w == -1.f);
  unsigned long long bal = __ballot(inv);
  const float ninv = (float)__popcll(bal);   // same in all waves
  int4 pk = {0, 0, 0, 0};
  if (!inv) {
    pk.x = (int)f2bf2(f0.x, f0.y); pk.y = (int)f2bf2(f0.z, f0.w);
    pk.z = (int)f2bf2(f1.x, f1.y); pk.w = (int)f2bf2(f1.z, f1.w);
  }
  const int src = 16 * w + m;        // agent for this wave's B-frag col m
  int g0 = __shfl(pk.x, src, 64), g1 = __shfl(pk.y, src, 64);
  int g2 = __shfl(pk.z, src, 64), g3 = __shfl(pk.w, src, 64);
  int invm = __shfl(inv, src, 64);
  int4 bv;
  if (q == 0)      bv = (int4){g0, g1, g2, g3};
  else if (q == 1) bv = (int4){invm ? 0 : 0x3f80, 0, 0, 0};  // k=8 bias input
  else             bv = (int4){0, 0, 0, 0};
  sh8 bs = __builtin_bit_cast(sh8, bv);

#pragma unroll
  for (int mt = 0; mt < 16; ++mt) {
    sh8 af = *(const sh8*)(w1f + (mt * 64 + lane) * 8);
    f32x4 z = {0.f, 0.f, 0.f, 0.f};
    f32x4 c = __builtin_amdgcn_mfma_f32_16x16x32_bf16(af, bs, z, 0, 0, 0);
    const int hidb = mt * 16 + q * 4;
    const int ks = hidb >> 5, qB = (hidb >> 3) & 3, js = hidb & 7;
    uint2 k0;
    k0.x = pkt(fmaxf(c[0], 0.f), fmaxf(c[1], 0.f));
    k0.y = pkt(fmaxf(c[2], 0.f), fmaxf(c[3], 0.f));
    *(uint2*)(&hlds[((w * 8 + ks) * 64 + qB * 16 + m) * 8 + js]) = k0;
  }
  __syncthreads();

  // ---- phase 2 ----
  f32x4 acc[4][4];
  f32x4 acc16[4];
#pragma unroll
  for (int Mt = 0; Mt < 4; ++Mt) {
#pragma unroll
    for (int i = 0; i < 4; ++i) {
      f32x4 z = {0.f, 0.f, 0.f, 0.f};
      acc[Mt][i] = z;
    }
    f32x4 z = {0.f, 0.f, 0.f, 0.f};
    acc16[Mt] = z;
  }

  const short* w2b = w2f + (size_t)(4 * w) * 8 * 512 + lane * 8;  // wave base
  const short* hb  = hlds + lane * 8;
  // prefetch tile-16 B-frags for this wave's two K-slices
  sh8 Bt0 = *(const sh8*)(w2f + (size_t)(16 * 8 + w) * 512 + lane * 8);
  sh8 Bt1 = *(const sh8*)(w2f + (size_t)(16 * 8 + w + 4) * 512 + lane * 8);

  sh8 A[4], Bf[4];
#pragma unroll
  for (int Mt = 0; Mt < 4; ++Mt) A[Mt] = *(const sh8*)(hb + (Mt * 8) * 512);
#pragma unroll
  for (int i = 0; i < 4; ++i)    Bf[i] = *(const sh8*)(w2b + (i * 8) * 512);

#pragma unroll
  for (int ks = 0; ks < 8; ++ks) {
    sh8 An[4], Bn[4];
    if (ks < 7) {
#pragma unroll
      for (int Mt = 0; Mt < 4; ++Mt)
        An[Mt] = *(const sh8*)(hb + (Mt * 8 + ks + 1) * 512);
#pragma unroll
      for (int i = 0; i < 4; ++i)
        Bn[i] = *(const sh8*)(w2b + (i * 8 + ks + 1) * 512);
    }
#pragma unroll
    for (int i = 0; i < 4; ++i)
#pragma unroll
      for (int Mt = 0; Mt < 4; ++Mt)
        acc[Mt][i] = __builtin_amdgcn_mfma_f32_16x16x32_bf16(A[Mt], Bf[i], acc[Mt][i], 0, 0, 0);
    if (ks == w) {
#pragma unroll
      for (int Mt = 0; Mt < 4; ++Mt)
        acc16[Mt] = __builtin_amdgcn_mfma_f32_16x16x32_bf16(A[Mt], Bt0, acc16[Mt], 0, 0, 0);
    }
    if (ks == w + 4) {
#pragma unroll
      for (int Mt = 0; Mt < 4; ++Mt)
        acc16[Mt] = __builtin_amdgcn_mfma_f32_16x16x32_bf16(A[Mt], Bt1, acc16[Mt], 0, 0, 0);
    }
    if (ks < 7) {
#pragma unroll
      for (int Mt = 0; Mt < 4; ++Mt) A[Mt] = An[Mt];
#pragma unroll
      for (int i = 0; i < 4; ++i)    Bf[i] = Bn[i];
    }
  }

  // ---- phase 3: relu + b2 + pool (regs/global only, before barrier) ----
#pragma unroll
  for (int i = 0; i < 4; ++i) {
    const int col = (4 * w + i) * 16 + m;          // 0..255
    const float b2c = b2[col];
    float ssum = 0.f;
#pragma unroll
    for (int Mt = 0; Mt < 4; ++Mt)
#pragma unroll
      for (int r = 0; r < 4; ++r)
        ssum += fmaxf(acc[Mt][i][r] + b2c, 0.f);
    ssum += __shfl_xor(ssum, 16, 64);
    ssum += __shfl_xor(ssum, 32, 64);
    ssum -= ninv * fmaxf(b2c, 0.f);
    if (q == 0)
      sob[(size_t)b * XPAD + CAR + col] = f2bf(ssum);
  }
  __syncthreads();                   // barrier-1: all hlds reads done
  if (m == 0) {                      // tile-16: only col 256 matters
#pragma unroll
    for (int Mt = 0; Mt < 4; ++Mt)
#pragma unroll
      for (int r = 0; r < 4; ++r)
        psum[w * 64 + Mt * 16 + q * 4 + r] = acc16[Mt][r];
  }
  __syncthreads();                   // barrier-2

  if (w == 0) {                      // combine K-partials, relu+b2, pool
    float tot = psum[lane] + psum[64 + lane] + psum[128 + lane] + psum[192 + lane];
    const float b2c = b2[256];
    float v = fmaxf(tot + b2c, 0.f);
#pragma unroll
    for (int msk = 1; msk < 64; msk <<= 1)
      v += __shfl_xor(v, msk, 64);
    if (lane == 0)
      sob[(size_t)b * XPAD + CAR + 256] = f2bf(v - ninv * fmaxf(b2c, 0.f));
  }
  if (w == 1 && lane < CAR)          // self-state
    sob[(size_t)b * XPAD + lane] = f2bf(s[(size_t)b * SROW + lane]);
  // pad cols 265..287: poison (finite bf16) x zero w3f rows = 0 in k_q
}

// ---------------------------------------------------------------------------
// K2: Q-head. 4 waves, 16 batch rows/block (512 blocks -> 2/CU).
// GEMM1: wave w owns hid-tiles 4w..4w+3; H fp32 -> LDS (stride 260).
// GEMM2: waves 0-1 (nt = w), K=256; C-layout store.
// ---------------------------------------------------------------------------
__global__ __launch_bounds__(256, 2)
void k_q(const short* __restrict__ sob, const short* __restrict__ w3f,
         const float* __restrict__ Qb1, const short* __restrict__ wq2f,
         const float* __restrict__ Qb2, float* __restrict__ out, int B) {
  __shared__ __align__(16) float H[16 * 260];   // 16.6 KB
  const int tid = threadIdx.x;
  const int w = tid >> 6, lane = tid & 63;
  const int q = lane >> 4, m = lane & 15;
  const int b0 = blockIdx.x * 16;
  int r0 = b0 + m; if (r0 >= B) r0 = B - 1;
  const short* xr0 = sob + (size_t)r0 * XPAD + q * 8;

  f32x4 acc1[4];
#pragma unroll
  for (int i = 0; i < 4; ++i) {
    f32x4 z = {0.f, 0.f, 0.f, 0.f};
    acc1[i] = z;
  }
#pragma unroll
  for (int ks = 0; ks < 9; ++ks) {
    sh8 A0 = *(const sh8*)(xr0 + ks * 32);
#pragma unroll
    for (int i = 0; i < 4; ++i) {
      sh8 Bf = *(const sh8*)(w3f + ((ks * 16 + 4 * w + i) * 64 + lane) * 8);
      acc1[i] = __builtin_amdgcn_mfma_f32_16x16x32_bf16(A0, Bf, acc1[i], 0, 0, 0);
    }
  }
#pragma unroll
  for (int i = 0; i < 4; ++i) {
    const int hcol = (4 * w + i) * 16 + m;
    const float bq = Qb1[hcol];
#pragma unroll
    for (int r = 0; r < 4; ++r)
      H[(q * 4 + r) * 260 + hcol] = fmaxf(acc1[i][r] + bq, 0.f);
  }
  __syncthreads();

  if (w < 2) {                       // GEMM2: H(16x256) @ Qw2 -> out
    const int nt2 = w;
    f32x4 acc2 = {0.f, 0.f, 0.f, 0.f};
#pragma unroll
    for (int ks = 0; ks < 8; ++ks) {
      const float* hp = H + m * 260 + ks * 32 + q * 8;
      float4 ha = ((const float4*)hp)[0], hb = ((const float4*)hp)[1];
      int4 t = {(int)f2bf2(ha.x, ha.y), (int)f2bf2(ha.z, ha.w),
                (int)f2bf2(hb.x, hb.y), (int)f2bf2(hb.z, hb.w)};
      sh8 A2 = __builtin_bit_cast(sh8, t);
      sh8 Bf = *(const sh8*)(wq2f + ((ks * 2 + nt2) * 64 + lane) * 8);
      acc2 = __builtin_amdgcn_mfma_f32_16x16x32_bf16(A2, Bf, acc2, 0, 0, 0);
    }
    const int act = nt2 * 16 + m;
    if (act < ADIM) {
      const float bq = Qb2[act];
#pragma unroll
      for (int r = 0; r < 4; ++r) {
        const int row = b0 + q * 4 + r;
        if (row < B) out[(size_t)row * ADIM + act] = acc2[r] + bq;
      }
    }
  }
}

extern "C" void kernel_launch(void* const* d_in, const int* in_sizes, int n_in,
                              void* d_out, int out_size, void* d_ws, size_t ws_size,
                              hipStream_t stream) {
  const float* s   = (const float*)d_in[0];
  const float* W1  = (const float*)d_in[1];
  const float* b1  = (const float*)d_in[2];
  const float* W2  = (const float*)d_in[3];
  const float* b2  = (const float*)d_in[4];
  const float* Qw1 = (const float*)d_in[5];
  const float* Qb1 = (const float*)d_in[6];
  const float* Qw2 = (const float*)d_in[7];
  const float* Qb2 = (const float*)d_in[8];
  float* out = (float*)d_out;
  const int B = in_sizes[0] / SROW;

  // ws: [sob B*288 bf16][w1f 8192][w2f 69632][w3f 73728][wq2f 8192] shorts
  char* wsb = (char*)d_ws;
  short* sob = (short*)wsb;
  size_t off = (size_t)B * XPAD * sizeof(short);
  short* w1f  = (short*)(wsb + off);            off += 8192 * 2;
  short* w2f  = (short*)(wsb + off);            off += 69632 * 2;
  short* w3f  = (short*)(wsb + off);            off += 73728 * 2;
  short* wq2f = (short*)(wsb + off);

  const int prep_elems = 8192 + 69632 + 73728 + 8192;
  k_prep<<<(prep_elems + 255) / 256, 256, 0, stream>>>(W1, b1, W2, Qw1, Qw2,
                                                       w1f, w2f, w3f, wq2f);
  k_enc<<<B, 256, 0, stream>>>(s, w1f, w2f, b2, sob, B);
  k_q<<<(B + 15) / 16, 256, 0, stream>>>(sob, w3f, Qb1, wq2f, Qb2, out, B);
}

// Round 12
// 163.830 us; speedup vs baseline: 4.4120x; 1.1223x over previous
//
#include <hip/hip_runtime.h>

#define CAR 8
#define SROW 520   // CAR + 64*CAR
#define HID 256
#define EOUT 257
#define XPAD 288   // padded Q-input row (shorts): 8 self + 257 enc + pad
#define ADIM 30

typedef __attribute__((ext_vector_type(8))) short sh8;
typedef __attribute__((ext_vector_type(4))) float f32x4;

__device__ __forceinline__ short f2bf(float f) {
  unsigned u = __builtin_bit_cast(unsigned, f);
  u += 0x7fffu + ((u >> 16) & 1u);   // RNE
  return (short)(u >> 16);
}
// pack two fp32 -> packed bf16x2 (RNE, 5 VALU)
__device__ __forceinline__ unsigned f2bf2(float a, float b) {
  unsigned ua = __builtin_bit_cast(unsigned, a);
  ua += 0x7fffu + ((ua >> 16) & 1u);
  unsigned ub = __builtin_bit_cast(unsigned, b);
  ub += 0x7fffu + ((ub >> 16) & 1u);
  return __builtin_amdgcn_perm(ub, ua, 0x07060302);  // [a.hi16 | b.hi16]
}
// pack two fp32 -> packed bf16x2 (TRUNC, 1 VALU) — h staging only
__device__ __forceinline__ unsigned pkt(float a, float b) {
  return __builtin_amdgcn_perm(__builtin_bit_cast(unsigned, b),
                               __builtin_bit_cast(unsigned, a), 0x07060302);
}

// ---------------------------------------------------------------------------
// Prep (R9-exact): swizzle weights to bf16 MFMA fragments (16x16x32:
// A[m=lane&15][k=quad*8+j], B[k=quad*8+j][n=lane&15], C/D row=quad*4+reg,
// col=lane&15).
// w1f : [W1;b1]^T as A [16 mt][64][8]  (k=8 row = b1)            (8192)
// w2f : [W2;b2] as B [17 nt][9 ks][64][8]  (k=256 row = b2)      (78336)
// w3f : Qw1 as B   [9 ks][16 nt][64][8], k = X-row idx           (73728)
// wq2f: Qw2 as B   [8 ks][2 nt][64][8]                           (8192)
// ---------------------------------------------------------------------------
__global__ void k_prep(const float* __restrict__ W1, const float* __restrict__ b1,
                       const float* __restrict__ W2, const float* __restrict__ b2,
                       const float* __restrict__ Qw1, const float* __restrict__ Qw2,
                       short* __restrict__ w1f, short* __restrict__ w2f,
                       short* __restrict__ w3f, short* __restrict__ wq2f) {
  int idx = blockIdx.x * 256 + threadIdx.x;
  if (idx < 8192) {                         // [W1;b1]^T as A
    int mt = idx >> 9, r = idx & 511, lane = r >> 3, j = r & 7;
    int quad = lane >> 4, m = lane & 15;
    int hid = mt * 16 + m;
    float v = (quad == 0) ? W1[j * HID + hid]
            : (quad == 1 && j == 0) ? b1[hid] : 0.0f;
    w1f[idx] = f2bf(v);
    return;
  }
  int i2 = idx - 8192;
  if (i2 < 78336) {                         // [W2;b2] as B, [nt][ks][64][8]
    int nt = i2 / 4608, r = i2 % 4608;
    int ks = r >> 9, r2 = r & 511, lane = r2 >> 3, j = r2 & 7;
    int quad = lane >> 4, m = lane & 15;
    int k = ks * 32 + quad * 8 + j, n = nt * 16 + m;
    float v = 0.0f;
    if (n < EOUT) {
      if (k < 256)       v = W2[k * EOUT + n];
      else if (k == 256) v = b2[n];         // bias row (input = valid flag)
    }
    w2f[i2] = f2bf(v);
    return;
  }
  int i3 = i2 - 78336;
  if (i3 < 73728) {                         // Qw1 as B
    int ks = i3 >> 13, r = i3 & 8191;
    int nt = r >> 9, r2 = r & 511, lane = r2 >> 3, j = r2 & 7;
    int quad = lane >> 4, m = lane & 15;
    int k = ks * 32 + quad * 8 + j, n = nt * 16 + m;
    float v = (k < 265) ? Qw1[k * HID + n] : 0.0f;
    w3f[i3] = f2bf(v);
    return;
  }
  int i4 = i3 - 73728;
  if (i4 < 8192) {                          // Qw2 as B
    int ks = i4 >> 10, r = i4 & 1023;
    int nt = r >> 9, r2 = r & 511, lane = r2 >> 3, j = r2 & 7;
    int quad = lane >> 4, m = lane & 15;
    int k = ks * 32 + quad * 8 + j, n = nt * 16 + m;
    float v = (n < ADIM) ? Qw2[k * ADIM + n] : 0.0f;
    wq2f[i4] = f2bf(v);
  }
}

// ---------------------------------------------------------------------------
// K1 (R9-exact, measured 95 us): encoder + pool, NB=1, 4 waves, 37 KB LDS,
// K=288 (b2+mask folded into GEMM as flag row).
// ---------------------------------------------------------------------------
__global__ __launch_bounds__(256, 3)
void k_enc(const float* __restrict__ s, const short* __restrict__ w1f,
           const short* __restrict__ w2f, short* __restrict__ sob, int B) {
  __shared__ __align__(16) short hlds[4 * 9 * 512];   // 36 KB
  __shared__ float psum[4][64];

  const int tid = threadIdx.x;
  const int w = tid >> 6, lane = tid & 63;
  const int q = lane >> 4, m = lane & 15;
  const int b = blockIdx.x;
  const float* srow0 = s + (size_t)b * SROW + CAR;

  // ---- phase 1: B-frag for agents 16w..16w+15 ----
  int dA = 0, dB = 0, invAi = 0;
  if (lane < 32) {                 // agent = 16w + (lane>>1), half = lane&1
    const float* sr = srow0 + (16 * w + (lane >> 1)) * CAR + (lane & 1) * 4;
    float4 f = *(const float4*)sr;
    int inv4 = (f.x == -1.f) | (f.y == -1.f) | (f.z == -1.f) | (f.w == -1.f);
    invAi = inv4 | __shfl_xor(inv4, 1, 64);
    if (!invAi) { dA = (int)f2bf2(f.x, f.y); dB = (int)f2bf2(f.z, f.w); }
  }
  const int src = 2 * m;
  int g0 = __shfl(dA, src, 64), g1 = __shfl(dB, src, 64);
  int g2 = __shfl(dA, src + 1, 64), g3 = __shfl(dB, src + 1, 64);
  int invm = __shfl(invAi, src, 64);      // flag of agent 16w+m (all lanes)
  const int flagbits = invm ? 0 : 0x3f80; // bf16 1.0
  int4 bv;
  if (q == 0)      bv = (int4){g0, g1, g2, g3};
  else if (q == 1) bv = (int4){flagbits, 0, 0, 0};   // k=8 bias input
  else             bv = (int4){0, 0, 0, 0};
  sh8 bs = __builtin_bit_cast(sh8, bv);

  // valid-flag row (k=256) for phase 2: A-frag lane (q,m): k=256+q*8+j.
  // only q==0,j==0 nonzero = flag(agent m).
  {
    int4 v4 = {(q == 0) ? flagbits : 0, 0, 0, 0};
    *(int4*)(&hlds[((w * 9 + 8) * 64 + lane) * 8]) = v4;
  }

#pragma unroll
  for (int mt = 0; mt < 16; ++mt) {
    sh8 af = *(const sh8*)(w1f + (mt * 64 + lane) * 8);
    f32x4 z = {0.f, 0.f, 0.f, 0.f};
    f32x4 c = __builtin_amdgcn_mfma_f32_16x16x32_bf16(af, bs, z, 0, 0, 0);
    const int hidb = mt * 16 + q * 4;
    const int ks = hidb >> 5, qB = (hidb >> 3) & 3, js = hidb & 7;
    uint2 k0;
    k0.x = pkt(fmaxf(c[0], 0.f), fmaxf(c[1], 0.f));
    k0.y = pkt(fmaxf(c[2], 0.f), fmaxf(c[3], 0.f));
    *(uint2*)(&hlds[((w * 9 + ks) * 64 + qB * 16 + m) * 8 + js]) = k0;
  }
  __syncthreads();

  // ---- phase 2: A/Bf double-buffered, base+imm addressing ----
  f32x4 acc[4][4];
  f32x4 acc16[4];
#pragma unroll
  for (int Mt = 0; Mt < 4; ++Mt) {
#pragma unroll
    for (int i = 0; i < 4; ++i) {
      f32x4 z = {0.f, 0.f, 0.f, 0.f};
      acc[Mt][i] = z;
    }
    f32x4 z = {0.f, 0.f, 0.f, 0.f};
    acc16[Mt] = z;
  }

  const short* w2b = w2f + (size_t)(4 * w) * 9 * 512 + lane * 8;  // wave base
  const short* hb  = hlds + lane * 8;

  sh8 A[4], Bf[4];
#pragma unroll
  for (int Mt = 0; Mt < 4; ++Mt) A[Mt] = *(const sh8*)(hb + Mt * 9 * 512);
#pragma unroll
  for (int i = 0; i < 4; ++i)    Bf[i] = *(const sh8*)(w2b + i * 9 * 512);

#pragma unroll
  for (int ks = 0; ks < 9; ++ks) {
    sh8 An[4], Bn[4];
    if (ks < 8) {
#pragma unroll
      for (int Mt = 0; Mt < 4; ++Mt)
        An[Mt] = *(const sh8*)(hb + (Mt * 9 + ks + 1) * 512);
#pragma unroll
      for (int i = 0; i < 4; ++i)
        Bn[i] = *(const sh8*)(w2b + (i * 9 + ks + 1) * 512);
    }
#pragma unroll
    for (int i = 0; i < 4; ++i)
#pragma unroll
      for (int Mt = 0; Mt < 4; ++Mt)
        acc[Mt][i] = __builtin_amdgcn_mfma_f32_16x16x32_bf16(A[Mt], Bf[i], acc[Mt][i], 0, 0, 0);
    if (ks == w || ks == w + 4 || (ks == 8 && w == 0)) {   // tile-16 K-split
      sh8 Bt = *(const sh8*)(w2f + (size_t)(16 * 9 + ks) * 512 + lane * 8);
#pragma unroll
      for (int Mt = 0; Mt < 4; ++Mt)
        acc16[Mt] = __builtin_amdgcn_mfma_f32_16x16x32_bf16(A[Mt], Bt, acc16[Mt], 0, 0, 0);
    }
    if (ks < 8) {
#pragma unroll
      for (int Mt = 0; Mt < 4; ++Mt) A[Mt] = An[Mt];
#pragma unroll
      for (int i = 0; i < 4; ++i)    Bf[i] = Bn[i];
    }
  }

  // ---- phase 3: relu + pool (bias already in acc; invalid agents = 0) ----
#pragma unroll
  for (int i = 0; i < 4; ++i) {
    const int col = (4 * w + i) * 16 + m;          // 0..255
    float ssum = 0.f;
#pragma unroll
    for (int Mt = 0; Mt < 4; ++Mt)
#pragma unroll
      for (int r = 0; r < 4; ++r)
        ssum += fmaxf(acc[Mt][i][r], 0.f);
    ssum += __shfl_xor(ssum, 16, 64);
    ssum += __shfl_xor(ssum, 32, 64);
    if (q == 0)
      sob[(size_t)b * XPAD + CAR + col] = f2bf(ssum);
  }
  if (m == 0) {                    // tile-16: only col 256 matters
#pragma unroll
    for (int Mt = 0; Mt < 4; ++Mt)
#pragma unroll
      for (int r = 0; r < 4; ++r)
        psum[w][Mt * 16 + q * 4 + r] = acc16[Mt][r];
  }
  __syncthreads();

  if (w == 0) {                    // combine K-partials, relu, pool col 256
    float tot = psum[0][lane] + psum[1][lane] + psum[2][lane] + psum[3][lane];
    float v = fmaxf(tot, 0.f);
#pragma unroll
    for (int msk = 1; msk < 64; msk <<= 1)
      v += __shfl_xor(v, msk, 64);
    if (lane == 0)
      sob[(size_t)b * XPAD + CAR + 256] = f2bf(v);
  }
  if (w == 1 && lane < CAR)        // self-state
    sob[(size_t)b * XPAD + lane] = f2bf(s[(size_t)b * SROW + lane]);
  // pad cols 265..287: poison (finite bf16) x zero w3f rows = 0 in k_q
}

// ---------------------------------------------------------------------------
// K2 (R11-exact): Q-head. 4 waves, 16 batch rows/block (512 blocks -> 2/CU).
// GEMM1: wave w owns hid-tiles 4w..4w+3; H fp32 -> LDS (stride 260).
// GEMM2: waves 0-1 (nt = w), K=256; C-layout store.
// ---------------------------------------------------------------------------
__global__ __launch_bounds__(256, 2)
void k_q(const short* __restrict__ sob, const short* __restrict__ w3f,
         const float* __restrict__ Qb1, const short* __restrict__ wq2f,
         const float* __restrict__ Qb2, float* __restrict__ out, int B) {
  __shared__ __align__(16) float H[16 * 260];   // 16.6 KB
  const int tid = threadIdx.x;
  const int w = tid >> 6, lane = tid & 63;
  const int q = lane >> 4, m = lane & 15;
  const int b0 = blockIdx.x * 16;
  int r0 = b0 + m; if (r0 >= B) r0 = B - 1;
  const short* xr0 = sob + (size_t)r0 * XPAD + q * 8;

  f32x4 acc1[4];
#pragma unroll
  for (int i = 0; i < 4; ++i) {
    f32x4 z = {0.f, 0.f, 0.f, 0.f};
    acc1[i] = z;
  }
#pragma unroll
  for (int ks = 0; ks < 9; ++ks) {
    sh8 A0 = *(const sh8*)(xr0 + ks * 32);
#pragma unroll
    for (int i = 0; i < 4; ++i) {
      sh8 Bf = *(const sh8*)(w3f + ((ks * 16 + 4 * w + i) * 64 + lane) * 8);
      acc1[i] = __builtin_amdgcn_mfma_f32_16x16x32_bf16(A0, Bf, acc1[i], 0, 0, 0);
    }
  }
#pragma unroll
  for (int i = 0; i < 4; ++i) {
    const int hcol = (4 * w + i) * 16 + m;
    const float bq = Qb1[hcol];
#pragma unroll
    for (int r = 0; r < 4; ++r)
      H[(q * 4 + r) * 260 + hcol] = fmaxf(acc1[i][r] + bq, 0.f);
  }
  __syncthreads();

  if (w < 2) {                       // GEMM2: H(16x256) @ Qw2 -> out
    const int nt2 = w;
    f32x4 acc2 = {0.f, 0.f, 0.f, 0.f};
#pragma unroll
    for (int ks = 0; ks < 8; ++ks) {
      const float* hp = H + m * 260 + ks * 32 + q * 8;
      float4 ha = ((const float4*)hp)[0], hb = ((const float4*)hp)[1];
      int4 t = {(int)f2bf2(ha.x, ha.y), (int)f2bf2(ha.z, ha.w),
                (int)f2bf2(hb.x, hb.y), (int)f2bf2(hb.z, hb.w)};
      sh8 A2 = __builtin_bit_cast(sh8, t);
      sh8 Bf = *(const sh8*)(wq2f + ((ks * 2 + nt2) * 64 + lane) * 8);
      acc2 = __builtin_amdgcn_mfma_f32_16x16x32_bf16(A2, Bf, acc2, 0, 0, 0);
    }
    const int act = nt2 * 16 + m;
    if (act < ADIM) {
      const float bq = Qb2[act];
#pragma unroll
      for (int r = 0; r < 4; ++r) {
        const int row = b0 + q * 4 + r;
        if (row < B) out[(size_t)row * ADIM + act] = acc2[r] + bq;
      }
    }
  }
}

extern "C" void kernel_launch(void* const* d_in, const int* in_sizes, int n_in,
                              void* d_out, int out_size, void* d_ws, size_t ws_size,
                              hipStream_t stream) {
  const float* s   = (const float*)d_in[0];
  const float* W1  = (const float*)d_in[1];
  const float* b1  = (const float*)d_in[2];
  const float* W2  = (const float*)d_in[3];
  const float* b2  = (const float*)d_in[4];
  const float* Qw1 = (const float*)d_in[5];
  const float* Qb1 = (const float*)d_in[6];
  const float* Qw2 = (const float*)d_in[7];
  const float* Qb2 = (const float*)d_in[8];
  float* out = (float*)d_out;
  const int B = in_sizes[0] / SROW;

  // ws: [sob B*288 bf16][w1f 8192][w2f 78336][w3f 73728][wq2f 8192] shorts
  char* wsb = (char*)d_ws;
  short* sob = (short*)wsb;
  size_t off = (size_t)B * XPAD * sizeof(short);
  short* w1f  = (short*)(wsb + off);            off += 8192 * 2;
  short* w2f  = (short*)(wsb + off);            off += 78336 * 2;
  short* w3f  = (short*)(wsb + off);            off += 73728 * 2;
  short* wq2f = (short*)(wsb + off);

  const int prep_elems = 8192 + 78336 + 73728 + 8192;
  k_prep<<<(prep_elems + 255) / 256, 256, 0, stream>>>(W1, b1, W2, b2, Qw1, Qw2,
                                                       w1f, w2f, w3f, wq2f);
  k_enc<<<B, 256, 0, stream>>>(s, w1f, w2f, sob, B);
  k_q<<<(B + 15) / 16, 256, 0, stream>>>(sob, w3f, Qb1, wq2f, Qb2, out, B);
}